// Round 21
// baseline (35.663 us; speedup 1.0000x reference)
//
#include <hip/hip_runtime.h>

#define WINDOW 11
#define H 512
#define W 512
#define OH 502            // H - WINDOW + 1
#define OW 502
#define NCH 3
#define BATCH 8
#define RSTRIPE 11        // one 11-output pass per wave
#define NSTRIPES 46       // 45 x 11 rows + 1 x 7 live rows (masked)
#define NGRP 5            // col groups: 4 x 118 outputs + 1 x 30
#define GRPW 118          // output cols per full group (64 lanes * 2 - 10 halo)
#define WAVES_PER_IMG (NSTRIPES * NGRP)                 // 230
#define NWAVES (BATCH * NCH * WAVES_PER_IMG)            // 5520
#define WAVES_PER_BATCH (NCH * WAVES_PER_IMG)           // 690
#define NXCD 8
#define CHUNK (NWAVES / NXCD)                           // 690 = one batch per XCD

#define NPIX_PER_BATCH (3.0f * 502.0f * 502.0f)   // 756012

// packed 2xf32: elementwise ops compile to v_pk_{add,mul,fma}_f32 on gfx950
typedef float v2f __attribute__((ext_vector_type(2)));

// fire-and-forget global->LDS copy: 64 lanes x 4B, LDS dst = base + lane*4
#define GL_LDS(gsrc, ldst)                                                    \
    __builtin_amdgcn_global_load_lds(                                         \
        (const __attribute__((address_space(1))) unsigned int*)(gsrc),        \
        (__attribute__((address_space(3))) unsigned int*)(ldst), 4, 0, 0)

template <int N>
__device__ __forceinline__ void vwait() {
    asm volatile("s_waitcnt vmcnt(%0)" :: "i"(N) : "memory");
    __builtin_amdgcn_sched_barrier(0);
}

// ---- gfx9 DPP inclusive wave scan (64 lanes), VALU-pipe only ----
template <int CTRL, int RM>
__device__ __forceinline__ float scan_step(float x) {
    int s = __builtin_amdgcn_update_dpp(0, __builtin_bit_cast(int, x),
                                        CTRL, RM, 0xf, false);
    return x + __builtin_bit_cast(float, s);
}
__device__ __forceinline__ float wave_iscan(float x) {
    x = scan_step<0x111, 0xf>(x);   // row_shr:1
    x = scan_step<0x112, 0xf>(x);   // row_shr:2
    x = scan_step<0x114, 0xf>(x);   // row_shr:4
    x = scan_step<0x118, 0xf>(x);   // row_shr:8
    x = scan_step<0x142, 0xa>(x);   // row_bcast:15 -> rows 1,3
    x = scan_step<0x143, 0xc>(x);   // row_bcast:31 -> rows 2,3
    return x;
}

__global__ __launch_bounds__(64) void ssim_main(const float* __restrict__ x,
                                                const float* __restrict__ y,
                                                float* __restrict__ partials) {
    // wave-private LDS staging: 21 rows x 128 cols x 2 images = 21 KB
    __shared__ float LX[21][128];
    __shared__ float LY[21][128];

    const int lane = threadIdx.x & 63;

    // XCD-chunked bijective swizzle: one batch (3 images) per XCD
    const int wg    = blockIdx.x;               // 0..5519, round-robins XCDs
    const int w_lin = (wg % NXCD) * CHUNK + wg / NXCD;

    const int img = w_lin / WAVES_PER_IMG;      // b*NCH + c
    const int rem = w_lin % WAVES_PER_IMG;
    const int grp = rem / NSTRIPES;
    const int rs  = rem % NSTRIPES;             // stripe minor -> L2-contiguous

    const int i0 = rs * RSTRIPE;
    const int i1 = min(i0 + RSTRIPE, OH);       // 11 rows; stripe 45: 7 live
    const int cstart = grp * GRPW;              // first staged/output col
    const int outw   = min(GRPW, OW - cstart);  // 118 or 30
    const bool tapActive = (2 * lane < outw);

    const float* __restrict__ xi = x + (size_t)img * H * W;
    const float* __restrict__ yi = y + (size_t)img * H * W;

    // per-lane global columns for the two 64-float halves of a staged row
    // (clamped for grp 4; clamped lanes feed only masked outputs)
    const int c_lo = min(cstart + lane, W - 1);
    const int c_hi = min(cstart + 64 + lane, W - 1);

    // --- issue ALL 84 loads fire-and-forget (21 rows x {x_lo,x_hi,y_lo,y_hi})
    // rows i0..i0+20 (row-clamped; clamped rows feed only masked outputs)
#pragma unroll
    for (int r = 0; r < 21; ++r) {
        const int row = min(i0 + r, H - 1);
        const float* bx = xi + (size_t)row * W;
        const float* by = yi + (size_t)row * W;
        GL_LDS(bx + c_lo, &LX[r][0]);
        GL_LDS(bx + c_hi, &LX[r][64]);
        GL_LDS(by + c_lo, &LY[r][0]);
        GL_LDS(by + c_hi, &LY[r][64]);
    }

    float acc = 0.f;

    // window sums via DPP scan over pair-totals T, then lane+5 fetches:
    //   We[l] = (S[l+5]-q1[l+5]) - (S[l]-T[l])    (cols 2l..2l+10)
    //   Wo[l] =  S[l+5] - S[l] + q1[l]            (cols 2l+1..2l+11)
#define COMPUTE(rowActive) do {                                               \
        float Tx = Qx.x + Qx.y, Ty = Qy.x + Qy.y;                             \
        float Tz = Qz.x + Qz.y, Tw = Qw.x + Qw.y;                             \
        float Sx = wave_iscan(Tx), Sy = wave_iscan(Ty);                       \
        float Sz = wave_iscan(Tz), Sw = wave_iscan(Tw);                       \
        int src = lane + 5;                                                   \
        float Ax = __shfl(Sx, src, 64), Ay = __shfl(Sy, src, 64);             \
        float Az = __shfl(Sz, src, 64), Aw = __shfl(Sw, src, 64);             \
        float Bx = __shfl(Qx.y, src, 64), By = __shfl(Qy.y, src, 64);         \
        float Bz = __shfl(Qz.y, src, 64), Bw = __shfl(Qw.y, src, 64);         \
        v2f Wx = {Ax - Bx - Sx + Tx, Ax - Sx + Qx.y};                         \
        v2f Wy = {Ay - By - Sy + Ty, Ay - Sy + Qy.y};                         \
        v2f Wz = {Az - Bz - Sz + Tz, Az - Sz + Qz.y};                         \
        v2f Ww = {Aw - Bw - Sw + Tw, Aw - Sw + Qw.y};                         \
        v2f mx  = Wx * (1.0f / 121.0f);                                       \
        v2f my  = Wy * (1.0f / 121.0f);                                       \
        v2f mxy = mx * my;                                                    \
        v2f m2  = mx * mx + my * my;                                          \
        v2f cov = (Ww - 121.0f * mxy) * (1.0f / 120.0f);                      \
        v2f vv  = (Wz - 121.0f * m2)  * (1.0f / 120.0f);                      \
        v2f num = (2.0f * mxy + 1e-4f) * (2.0f * cov + 9e-4f);                \
        v2f den = (m2 + 1e-4f) * (vv + 9e-4f);                                \
        float r = num.x * __builtin_amdgcn_rcpf(den.x)                        \
                + num.y * __builtin_amdgcn_rcpf(den.y);                       \
        acc += (tapActive & (rowActive)) ? r : 0.f;                           \
    } while (0)

    // --- init: wait for rows 0..10 (first 44 ops -> outstanding <= 40) ---
    vwait<40>();
    v2f Qx = 0.f, Qy = 0.f, Qz = 0.f, Qw = 0.f;
#pragma unroll
    for (int r = 0; r < WINDOW; ++r) {
        v2f a = *(const v2f*)&LX[r][2 * lane];
        v2f b = *(const v2f*)&LY[r][2 * lane];
        Qx += a;
        Qy += b;
        Qz += a * a + b * b;
        Qw += a * b;
    }
    COMPUTE(true);                        // output row i0 (always < OH)

    // --- 10 slide+compute steps; counted waits: row 11+U needs first
    // 4*(12+U) ops done -> outstanding <= 36-4U ---
#define STEP(U, N) do {                                               \
        vwait<N>();                                                   \
        v2f nx = *(const v2f*)&LX[11 + (U)][2 * lane];                \
        v2f ny = *(const v2f*)&LY[11 + (U)][2 * lane];                \
        v2f ox = *(const v2f*)&LX[(U)][2 * lane];                     \
        v2f oy = *(const v2f*)&LY[(U)][2 * lane];                     \
        Qx += nx - ox;                                                \
        Qy += ny - oy;                                                \
        Qz += nx * nx + ny * ny - ox * ox - oy * oy;                  \
        Qw += nx * ny - ox * oy;                                      \
        COMPUTE(i0 + (U) + 1 < i1);                                   \
    } while (0)

    STEP(0, 36); STEP(1, 32); STEP(2, 28); STEP(3, 24); STEP(4, 20);
    STEP(5, 16); STEP(6, 12); STEP(7, 8);  STEP(8, 4);  STEP(9, 0);

    // --- per-wave reduction (fixed order, deterministic), no atomics ---
    for (int off = 32; off > 0; off >>= 1)
        acc += __shfl_down(acc, off, 64);
    if (lane == 0) partials[w_lin] = acc;   // batch-contiguous layout
}

__global__ __launch_bounds__(64) void ssim_reduce(const float* __restrict__ partials,
                                                  float* __restrict__ out) {
    const int b    = blockIdx.x;           // one wave per batch element
    const int lane = threadIdx.x & 63;
    float s = 0.f;
    for (int k = lane; k < WAVES_PER_BATCH; k += 64)   // 690, fixed order
        s += partials[b * WAVES_PER_BATCH + k];
    for (int off = 32; off > 0; off >>= 1)
        s += __shfl_down(s, off, 64);
    if (lane == 0)
        out[b] = (1.0f - s / NPIX_PER_BATCH) * 0.5f;
}

extern "C" void kernel_launch(void* const* d_in, const int* in_sizes, int n_in,
                              void* d_out, int out_size, void* d_ws, size_t ws_size,
                              hipStream_t stream) {
    const float* x = (const float*)d_in[0];
    const float* y = (const float*)d_in[1];
    float* out      = (float*)d_out;
    float* partials = (float*)d_ws;   // 5520 floats, fully overwritten each call

    ssim_main<<<NWAVES, 64, 0, stream>>>(x, y, partials);
    ssim_reduce<<<BATCH, 64, 0, stream>>>(partials, out);
}

// Round 22
// 28.662 us; speedup vs baseline: 1.2443x; 1.2443x over previous
//
#include <hip/hip_runtime.h>

#define WINDOW 11
#define H 512
#define W 512
#define OH 502            // H - WINDOW + 1
#define OW 502
#define NCH 3
#define BATCH 8
#define RSTRIPE 11        // one unrolled 11-pass; FIFO slot = unroll index
#define NSTRIPES 46       // 45 x 11 rows + 1 x 7 live rows (masked)
#define NGRP 5            // col groups: 4 x 118 outputs + 1 x 30 (float2 lanes)
#define GRPW 118          // output cols per full group (64 lanes * 2 - 10 halo)
#define WAVES_PER_IMG (NSTRIPES * NGRP)                 // 230
#define NWAVES (BATCH * NCH * WAVES_PER_IMG)            // 5520
#define NBLOCKS (NWAVES / 4)                            // 1380 (4 waves/block)
#define WAVES_PER_BATCH (NCH * WAVES_PER_IMG)           // 690
#define NXCD 8

#define NPIX_PER_BATCH (3.0f * 502.0f * 502.0f)   // 756012

// packed 2xf32: elementwise ops compile to v_pk_{add,mul,fma}_f32 on gfx950
typedef float v2f __attribute__((ext_vector_type(2)));

// ---- gfx9 DPP inclusive wave scan (64 lanes), VALU-pipe only, 4-cyc hops ----
template <int CTRL, int RM>
__device__ __forceinline__ float scan_step(float x) {
    int s = __builtin_amdgcn_update_dpp(0, __builtin_bit_cast(int, x),
                                        CTRL, RM, 0xf, false);
    return x + __builtin_bit_cast(float, s);
}
__device__ __forceinline__ float wave_iscan(float x) {
    x = scan_step<0x111, 0xf>(x);   // row_shr:1
    x = scan_step<0x112, 0xf>(x);   // row_shr:2
    x = scan_step<0x114, 0xf>(x);   // row_shr:4
    x = scan_step<0x118, 0xf>(x);   // row_shr:8
    x = scan_step<0x142, 0xa>(x);   // row_bcast:15 -> rows 1,3
    x = scan_step<0x143, 0xc>(x);   // row_bcast:31 -> rows 2,3
    return x;
}

__global__ __launch_bounds__(256) void ssim_main(const float* __restrict__ x,
                                                 const float* __restrict__ y,
                                                 float* __restrict__ partials) {
    const int t    = threadIdx.x;
    const int lane = t & 63;
    const int widx = t >> 6;                    // wave within block (0..3)

    // Bijective XCD-chunked swizzle on BLOCK index (m204 variant: 1380 % 8 != 0)
    const int wg  = blockIdx.x;                 // 0..1379, round-robins XCDs
    const int q   = NBLOCKS / NXCD;             // 172
    const int r8  = NBLOCKS % NXCD;             // 4
    const int xcd = wg % NXCD, bidx = wg / NXCD;
    const int blk_lin = (xcd < r8) ? (xcd * (q + 1) + bidx)
                                   : (r8 * (q + 1) + (xcd - r8) * q + bidx);
    const int w_lin = blk_lin * 4 + widx;       // contiguous work id

    const int img = w_lin / WAVES_PER_IMG;      // b*NCH + c
    const int rem = w_lin % WAVES_PER_IMG;
    const int grp = rem / NSTRIPES;
    const int rs  = rem % NSTRIPES;             // stripe minor -> L2-contiguous

    const int i0 = rs * RSTRIPE;
    const int i1 = min(i0 + RSTRIPE, OH);       // 11 rows; stripe 45: 7 live
    const int cstart = grp * GRPW;              // first staged/output col
    const int outw   = min(GRPW, OW - cstart);  // 118 or 30
    // clamped column pair: out-of-range lanes read real (unused) data
    const int c0 = min(cstart + 2 * lane, W - 2);
    const bool tapActive = (2 * lane < outw);

    const float* __restrict__ xc = x + (size_t)img * H * W + c0;
    const float* __restrict__ yc = y + (size_t)img * H * W + c0;

    // --- 11-row register FIFO: each input row loaded exactly ONCE ---
    v2f fx[11], fy[11];
    // per-column-pair sums {col 2l, col 2l+1}: x, y, x2+y2, xy
    v2f Qx = 0.f, Qy = 0.f, Qz = 0.f, Qw = 0.f;
#pragma unroll
    for (int r = 0; r < WINDOW; ++r) {
        v2f a = *(const v2f*)(xc + (size_t)(i0 + r) * W);
        v2f b = *(const v2f*)(yc + (size_t)(i0 + r) * W);
        fx[r] = a; fy[r] = b;
        Qx += a;
        Qy += b;
        Qz += a * a + b * b;
        Qw += a * b;
    }

    // incoming row (row i+11), loaded one iteration ahead
    v2f nx, ny;
#define LDNEW(j) do {                                                \
        int jc_ = min((j), H - 1);                                   \
        nx = *(const v2f*)(xc + (size_t)jc_ * W);                    \
        ny = *(const v2f*)(yc + (size_t)jc_ * W);                    \
    } while (0)

    // packed slide: old row from FIFO slot u, new row from (nx, ny)
#define SLIDE(u) do {                                                 \
        Qx += nx - fx[u];                                             \
        Qy += ny - fy[u];                                             \
        Qz += nx * nx + ny * ny - fx[u] * fx[u] - fy[u] * fy[u];      \
        Qw += nx * ny - fx[u] * fy[u];                                \
        fx[u] = nx; fy[u] = ny;                                       \
    } while (0)

    float acc = 0.f;

    // window sums via DPP scan over pair-totals T, then lane+5 fetches:
    //   We[l] = (S[l+5]-q1[l+5]) - (S[l]-T[l])    (cols 2l..2l+10)
    //   Wo[l] =  S[l+5] - S[l] + q1[l]            (cols 2l+1..2l+11)
#define COMPUTE(rowActive) do {                                               \
        float Tx = Qx.x + Qx.y, Ty = Qy.x + Qy.y;                             \
        float Tz = Qz.x + Qz.y, Tw = Qw.x + Qw.y;                             \
        float Sx = wave_iscan(Tx), Sy = wave_iscan(Ty);                       \
        float Sz = wave_iscan(Tz), Sw = wave_iscan(Tw);                       \
        int src = lane + 5;                                                   \
        float Ax = __shfl(Sx, src, 64), Ay = __shfl(Sy, src, 64);             \
        float Az = __shfl(Sz, src, 64), Aw = __shfl(Sw, src, 64);             \
        float Bx = __shfl(Qx.y, src, 64), By = __shfl(Qy.y, src, 64);         \
        float Bz = __shfl(Qz.y, src, 64), Bw = __shfl(Qw.y, src, 64);         \
        v2f Wx = {Ax - Bx - Sx + Tx, Ax - Sx + Qx.y};                         \
        v2f Wy = {Ay - By - Sy + Ty, Ay - Sy + Qy.y};                         \
        v2f Wz = {Az - Bz - Sz + Tz, Az - Sz + Qz.y};                         \
        v2f Ww = {Aw - Bw - Sw + Tw, Aw - Sw + Qw.y};                         \
        /* packed SSIM for the {even, odd} window pair */                     \
        v2f mx  = Wx * (1.0f / 121.0f);                                       \
        v2f my  = Wy * (1.0f / 121.0f);                                       \
        v2f mxy = mx * my;                                                    \
        v2f m2  = mx * mx + my * my;                                          \
        v2f cov = (Ww - 121.0f * mxy) * (1.0f / 120.0f);                      \
        v2f vv  = (Wz - 121.0f * m2)  * (1.0f / 120.0f);                      \
        v2f num = (2.0f * mxy + 1e-4f) * (2.0f * cov + 9e-4f);                \
        v2f den = (m2 + 1e-4f) * (vv + 9e-4f);                                \
        float r = num.x * __builtin_amdgcn_rcpf(den.x)                        \
                + num.y * __builtin_amdgcn_rcpf(den.y);                       \
        acc += (tapActive & (rowActive)) ? r : 0.f;                           \
    } while (0)

    // --- single unrolled 11-pass: FIFO slot index is the unroll index ---
    LDNEW(i0 + WINDOW);                   // prefetch first incoming row
#pragma unroll
    for (int u = 0; u < 11; ++u) {
        const int i = i0 + u;
        COMPUTE(i < i1);                  // window sums + SSIM for row i
        SLIDE(u);                         // retire row i, absorb row i+11
        LDNEW(i + WINDOW + 1);            // prefetch next incoming (clamped)
    }

    // --- per-wave reduction (fixed order, deterministic), no atomics,
    // no cross-wave coupling, no barriers ---
    for (int off = 32; off > 0; off >>= 1)
        acc += __shfl_down(acc, off, 64);
    if (lane == 0) partials[w_lin] = acc;   // batch-contiguous layout
}

__global__ __launch_bounds__(64) void ssim_reduce(const float* __restrict__ partials,
                                                  float* __restrict__ out) {
    const int b    = blockIdx.x;           // one wave per batch element
    const int lane = threadIdx.x & 63;
    float s = 0.f;
    for (int k = lane; k < WAVES_PER_BATCH; k += 64)   // 690, fixed order
        s += partials[b * WAVES_PER_BATCH + k];
    for (int off = 32; off > 0; off >>= 1)
        s += __shfl_down(s, off, 64);
    if (lane == 0)
        out[b] = (1.0f - s / NPIX_PER_BATCH) * 0.5f;
}

extern "C" void kernel_launch(void* const* d_in, const int* in_sizes, int n_in,
                              void* d_out, int out_size, void* d_ws, size_t ws_size,
                              hipStream_t stream) {
    const float* x = (const float*)d_in[0];
    const float* y = (const float*)d_in[1];
    float* out      = (float*)d_out;
    float* partials = (float*)d_ws;   // 5520 floats, fully overwritten each call

    ssim_main<<<NBLOCKS, 256, 0, stream>>>(x, y, partials);
    ssim_reduce<<<BATCH, 64, 0, stream>>>(partials, out);
}

// Round 23
// 28.198 us; speedup vs baseline: 1.2648x; 1.0165x over previous
//
#include <hip/hip_runtime.h>

#define WINDOW 11
#define H 512
#define W 512
#define OH 502            // H - WINDOW + 1
#define OW 502
#define NCH 3
#define BATCH 8
#define RSTRIPE 11        // one unrolled 11-pass; FIFO slot = unroll index
#define NSTRIPES 46       // 45 x 11 rows + 1 x 7 live rows (masked)
#define NGRP 5            // col groups: 4 x 118 outputs + 1 x 30 (float2 lanes)
#define GRPW 118          // output cols per full group (64 lanes * 2 - 10 halo)
#define WAVES_PER_IMG (NSTRIPES * NGRP)                 // 230
#define NWAVES (BATCH * NCH * WAVES_PER_IMG)            // 5520
#define WAVES_PER_BATCH (NCH * WAVES_PER_IMG)           // 690
#define NXCD 8
#define CHUNK (NWAVES / NXCD)                           // 690 = one batch per XCD

#define NPIX_PER_BATCH (3.0f * 502.0f * 502.0f)   // 756012

// packed 2xf32: elementwise ops compile to v_pk_{add,mul,fma}_f32 on gfx950
typedef float v2f __attribute__((ext_vector_type(2)));

// ---- gfx9 DPP inclusive wave scan (64 lanes), VALU-pipe only, 4-cyc hops ----
template <int CTRL, int RM>
__device__ __forceinline__ float scan_step(float x) {
    int s = __builtin_amdgcn_update_dpp(0, __builtin_bit_cast(int, x),
                                        CTRL, RM, 0xf, false);
    return x + __builtin_bit_cast(float, s);
}
__device__ __forceinline__ float wave_iscan(float x) {
    x = scan_step<0x111, 0xf>(x);   // row_shr:1
    x = scan_step<0x112, 0xf>(x);   // row_shr:2
    x = scan_step<0x114, 0xf>(x);   // row_shr:4
    x = scan_step<0x118, 0xf>(x);   // row_shr:8
    x = scan_step<0x142, 0xa>(x);   // row_bcast:15 -> rows 1,3
    x = scan_step<0x143, 0xc>(x);   // row_bcast:31 -> rows 2,3
    return x;
}

__global__ __launch_bounds__(64) void ssim_main(const float* __restrict__ x,
                                                const float* __restrict__ y,
                                                float* __restrict__ partials) {
    const int lane = threadIdx.x & 63;

    // XCD-chunked bijective swizzle: one batch (3 images) per XCD -> halo
    // rows shared between stripes re-read XCD-L2-locally.
    const int wg    = blockIdx.x;               // 0..5519, round-robins XCDs
    const int w_lin = (wg % NXCD) * CHUNK + wg / NXCD;

    const int img = w_lin / WAVES_PER_IMG;      // b*NCH + c
    const int rem = w_lin % WAVES_PER_IMG;
    const int grp = rem / NSTRIPES;
    const int rs  = rem % NSTRIPES;             // stripe minor -> L2-contiguous

    const int i0 = rs * RSTRIPE;
    const int i1 = min(i0 + RSTRIPE, OH);       // 11 rows; stripe 45: 7 live
    const int cstart = grp * GRPW;              // first staged/output col
    const int outw   = min(GRPW, OW - cstart);  // 118 or 30
    // clamped column pair: out-of-range lanes read real (unused) data
    const int c0 = min(cstart + 2 * lane, W - 2);
    const bool tapActive = (2 * lane < outw);

    const float* __restrict__ xc = x + (size_t)img * H * W + c0;
    const float* __restrict__ yc = y + (size_t)img * H * W + c0;

    // --- 11-row register FIFO: each input row loaded exactly ONCE ---
    v2f fx[11], fy[11];
    // per-column-pair sums {col 2l, col 2l+1}: x, y, x2+y2, xy
    v2f Qx = 0.f, Qy = 0.f, Qz = 0.f, Qw = 0.f;
#pragma unroll
    for (int r = 0; r < WINDOW; ++r) {
        v2f a = *(const v2f*)(xc + (size_t)(i0 + r) * W);
        v2f b = *(const v2f*)(yc + (size_t)(i0 + r) * W);
        fx[r] = a; fy[r] = b;
        Qx += a;
        Qy += b;
        Qz += a * a + b * b;
        Qw += a * b;
    }

    // incoming row (row i+11), loaded one iteration ahead
    v2f nx, ny;
#define LDNEW(j) do {                                                \
        int jc_ = min((j), H - 1);                                   \
        nx = *(const v2f*)(xc + (size_t)jc_ * W);                    \
        ny = *(const v2f*)(yc + (size_t)jc_ * W);                    \
    } while (0)

    // packed slide: old row from FIFO slot u, new row from (nx, ny)
#define SLIDE(u) do {                                                 \
        Qx += nx - fx[u];                                             \
        Qy += ny - fy[u];                                             \
        Qz += nx * nx + ny * ny - fx[u] * fx[u] - fy[u] * fy[u];      \
        Qw += nx * ny - fx[u] * fy[u];                                \
        fx[u] = nx; fy[u] = ny;                                       \
    } while (0)

    float acc = 0.f;

    // window sums via DPP scan over pair-totals T, then lane+5 fetches:
    //   We[l] = (S[l+5]-q1[l+5]) - (S[l]-T[l])    (cols 2l..2l+10)
    //   Wo[l] =  S[l+5] - S[l] + q1[l]            (cols 2l+1..2l+11)
#define COMPUTE(rowActive) do {                                               \
        float Tx = Qx.x + Qx.y, Ty = Qy.x + Qy.y;                             \
        float Tz = Qz.x + Qz.y, Tw = Qw.x + Qw.y;                             \
        float Sx = wave_iscan(Tx), Sy = wave_iscan(Ty);                       \
        float Sz = wave_iscan(Tz), Sw = wave_iscan(Tw);                       \
        int src = lane + 5;                                                   \
        float Ax = __shfl(Sx, src, 64), Ay = __shfl(Sy, src, 64);             \
        float Az = __shfl(Sz, src, 64), Aw = __shfl(Sw, src, 64);             \
        float Bx = __shfl(Qx.y, src, 64), By = __shfl(Qy.y, src, 64);         \
        float Bz = __shfl(Qz.y, src, 64), Bw = __shfl(Qw.y, src, 64);         \
        v2f Wx = {Ax - Bx - Sx + Tx, Ax - Sx + Qx.y};                         \
        v2f Wy = {Ay - By - Sy + Ty, Ay - Sy + Qy.y};                         \
        v2f Wz = {Az - Bz - Sz + Tz, Az - Sz + Qz.y};                         \
        v2f Ww = {Aw - Bw - Sw + Tw, Aw - Sw + Qw.y};                         \
        /* packed SSIM for the {even, odd} window pair */                     \
        v2f mx  = Wx * (1.0f / 121.0f);                                       \
        v2f my  = Wy * (1.0f / 121.0f);                                       \
        v2f mxy = mx * my;                                                    \
        v2f m2  = mx * mx + my * my;                                          \
        v2f cov = (Ww - 121.0f * mxy) * (1.0f / 120.0f);                      \
        v2f vv  = (Wz - 121.0f * m2)  * (1.0f / 120.0f);                      \
        v2f num = (2.0f * mxy + 1e-4f) * (2.0f * cov + 9e-4f);                \
        v2f den = (m2 + 1e-4f) * (vv + 9e-4f);                                \
        float r = num.x * __builtin_amdgcn_rcpf(den.x)                        \
                + num.y * __builtin_amdgcn_rcpf(den.y);                       \
        acc += (tapActive & (rowActive)) ? r : 0.f;                           \
    } while (0)

    // --- single unrolled 11-pass: FIFO slot index is the unroll index ---
    LDNEW(i0 + WINDOW);                   // prefetch first incoming row
#pragma unroll
    for (int u = 0; u < 11; ++u) {
        const int i = i0 + u;
        COMPUTE(i < i1);                  // window sums + SSIM for row i
        SLIDE(u);                         // retire row i, absorb row i+11
        LDNEW(i + WINDOW + 1);            // prefetch next incoming (clamped)
    }

    // --- per-wave reduction (fixed order, deterministic), no atomics ---
    for (int off = 32; off > 0; off >>= 1)
        acc += __shfl_down(acc, off, 64);
    if (lane == 0) partials[w_lin] = acc;   // batch-contiguous layout
}

__global__ __launch_bounds__(64) void ssim_reduce(const float* __restrict__ partials,
                                                  float* __restrict__ out) {
    const int b    = blockIdx.x;           // one wave per batch element
    const int lane = threadIdx.x & 63;
    float s = 0.f;
    for (int k = lane; k < WAVES_PER_BATCH; k += 64)   // 690, fixed order
        s += partials[b * WAVES_PER_BATCH + k];
    for (int off = 32; off > 0; off >>= 1)
        s += __shfl_down(s, off, 64);
    if (lane == 0)
        out[b] = (1.0f - s / NPIX_PER_BATCH) * 0.5f;
}

extern "C" void kernel_launch(void* const* d_in, const int* in_sizes, int n_in,
                              void* d_out, int out_size, void* d_ws, size_t ws_size,
                              hipStream_t stream) {
    const float* x = (const float*)d_in[0];
    const float* y = (const float*)d_in[1];
    float* out      = (float*)d_out;
    float* partials = (float*)d_ws;   // 5520 floats, fully overwritten each call

    ssim_main<<<NWAVES, 64, 0, stream>>>(x, y, partials);
    ssim_reduce<<<BATCH, 64, 0, stream>>>(partials, out);
}